// Round 6
// baseline (545.070 us; speedup 1.0000x reference)
//
#include <hip/hip_runtime.h>
#include <hip/hip_bf16.h>
#include <stdint.h>
#include <stddef.h>

typedef __attribute__((ext_vector_type(8))) short short8;
typedef __attribute__((ext_vector_type(4))) float f32x4;

#define NTOK 32768
#define DIN 512
#define HID 1024
#define DOUT 256
#define NEXP 10

#define TW1_BLOCKS 1280   // W1 transpose: 16x8 tiles x 10 experts
#define TW2_BLOCKS 640    // W2 transpose: 4x16 tiles x 10 experts
#define RT_BLOCKS  512    // router: 64 tokens/block

__device__ __forceinline__ unsigned short f2bf(float f) {
  unsigned int u = __float_as_uint(f);
  u += 0x7fffu + ((u >> 16) & 1u);   // round-to-nearest-even
  return (unsigned short)(u >> 16);
}

__device__ __forceinline__ unsigned long long pack4bf(float4 v) {
  return (unsigned long long)f2bf(v.x) | ((unsigned long long)f2bf(v.y) << 16) |
         ((unsigned long long)f2bf(v.z) << 32) | ((unsigned long long)f2bf(v.w) << 48);
}

// async 16B/lane global->LDS DMA (dest = wave-uniform base + lane*16)
__device__ __forceinline__ void gld16(void* lds, const void* g) {
  __builtin_amdgcn_global_load_lds(
      (const __attribute__((address_space(1))) unsigned int*)g,
      (__attribute__((address_space(3))) unsigned int*)lds, 16, 0, 0);
}

union PrepSmem {
  unsigned short tile[64][72];
  struct {
    int i0[64]; int i1[64]; float w0[64]; float w1[64];
    int hist[NEXP]; int base_[NEXP]; int loc[NEXP];
  } rt;
};

// ---- fused prep: W1/W2 transpose+convert, router (+out zeroing), Wr inline ----
__global__ __launch_bounds__(256) void k_prep(
    const float* __restrict__ x, const float* __restrict__ spike,
    const float* __restrict__ Wr, const float* __restrict__ br,
    const float* __restrict__ W1, const float* __restrict__ W2,
    unsigned short* __restrict__ xb, unsigned short* __restrict__ w1t,
    unsigned short* __restrict__ w2t, int* __restrict__ cnt,
    int* __restrict__ tok, float* __restrict__ wgt, float* __restrict__ out) {
  __shared__ PrepSmem sm;
  int bid = blockIdx.x;
  int tid = threadIdx.x;

  if (bid < TW1_BLOCKS + TW2_BLOCKS) {
    // ---------------- transpose path: [E][R][C] f32 -> [E][C][R] bf16 -------
    const float* in; unsigned short* outp; int R, C, bx, by, bz;
    if (bid < TW1_BLOCKS) {
      int r = bid; bz = r >> 7; r &= 127; by = r >> 4; bx = r & 15;
      in = W1; outp = w1t; R = DIN; C = HID;
    } else {
      int r = bid - TW1_BLOCKS; bz = r >> 6; r &= 63; by = r >> 2; bx = r & 3;
      in = W2; outp = w2t; R = HID; C = DOUT;
    }
    const float* ip = in + ((size_t)bz * R + by * 64) * C + bx * 64;
    int rr = tid >> 2, c0 = (tid & 3) * 16;
    const float* p = ip + (size_t)rr * C + c0;
#pragma unroll
    for (int j = 0; j < 16; j += 4) {
      float4 v = *(const float4*)(p + j);
      sm.tile[rr][c0 + j + 0] = f2bf(v.x);
      sm.tile[rr][c0 + j + 1] = f2bf(v.y);
      sm.tile[rr][c0 + j + 2] = f2bf(v.z);
      sm.tile[rr][c0 + j + 3] = f2bf(v.w);
    }
    __syncthreads();
    unsigned short* op = outp + ((size_t)bz * C + bx * 64) * R + by * 64;
    int c = tid >> 2, r0 = (tid & 3) * 16;
    unsigned short* q = op + (size_t)c * R + r0;
    union { short8 v; unsigned short u[8]; } t0, t1;
#pragma unroll
    for (int j = 0; j < 8; j++) { t0.u[j] = sm.tile[r0 + j][c]; t1.u[j] = sm.tile[r0 + 8 + j][c]; }
    *(short8*)(q) = t0.v;
    *(short8*)(q + 8) = t1.v;
    return;
  }

  // ---------------- router path (also zeroes its out slice) -----------------
  int rb = bid - (TW1_BLOCKS + TW2_BLOCKS);
  int wave = tid >> 6, lane = tid & 63;
  {
    float4 z = {0.f, 0.f, 0.f, 0.f};
    float4* ob = (float4*)(out + (size_t)rb * 64 * DOUT);
#pragma unroll
    for (int i = 0; i < 16; i++) ob[i * 256 + tid] = z;   // 64*256 floats
  }
  if (tid < NEXP) { sm.rt.hist[tid] = 0; sm.rt.loc[tid] = 0; }
  __syncthreads();
  // preload router weights transposed from Wr [512][10] into registers
  float4 wv[NEXP][2];
  float brr[NEXP];
#pragma unroll
  for (int e = 0; e < NEXP; e++) {
    brr[e] = br[e];
#pragma unroll
    for (int h = 0; h < 2; h++) {
      int d0 = h * 256 + lane * 4;
      wv[e][h] = (float4){Wr[(size_t)(d0 + 0) * NEXP + e], Wr[(size_t)(d0 + 1) * NEXP + e],
                          Wr[(size_t)(d0 + 2) * NEXP + e], Wr[(size_t)(d0 + 3) * NEXP + e]};
    }
  }
  for (int t = 0; t < 16; t++) {
    int slot = wave * 16 + t;
    int b = rb * 64 + slot;
    const float4* xr4 = (const float4*)(x + (size_t)b * DIN);
    float4 xv0 = xr4[lane], xv1 = xr4[64 + lane];
    *(unsigned long long*)(xb + (size_t)b * DIN + lane * 4) = pack4bf(xv0);
    *(unsigned long long*)(xb + (size_t)b * DIN + 256 + lane * 4) = pack4bf(xv1);
    float lg[NEXP];
#pragma unroll
    for (int e = 0; e < NEXP; e++) {
      lg[e] = xv0.x * wv[e][0].x + xv0.y * wv[e][0].y + xv0.z * wv[e][0].z + xv0.w * wv[e][0].w +
              xv1.x * wv[e][1].x + xv1.y * wv[e][1].y + xv1.z * wv[e][1].z + xv1.w * wv[e][1].w;
    }
#pragma unroll
    for (int off = 32; off > 0; off >>= 1) {
#pragma unroll
      for (int e = 0; e < NEXP; e++) lg[e] += __shfl_xor(lg[e], off);
    }
    float sv = spike[(size_t)b * 16 + (lane & 15)];
    sv += __shfl_xor(sv, 8); sv += __shfl_xor(sv, 4);
    sv += __shfl_xor(sv, 2); sv += __shfl_xor(sv, 1);
    float avg = sv * 0.0625f;
#pragma unroll
    for (int e = 0; e < NEXP; e++) lg[e] += brr[e];
    lg[8] += avg; lg[9] += avg;
    float mx = lg[0];
#pragma unroll
    for (int e = 1; e < NEXP; e++) mx = fmaxf(mx, lg[e]);
    float p[NEXP], ps = 0.f;
#pragma unroll
    for (int e = 0; e < NEXP; e++) { p[e] = __expf(lg[e] - mx); ps += p[e]; }
    int i0 = 0; float p0 = p[0];
#pragma unroll
    for (int e = 1; e < NEXP; e++) if (p[e] > p0) { p0 = p[e]; i0 = e; }
    float p1 = -1.f; int i1 = 0;
#pragma unroll
    for (int e = 0; e < NEXP; e++) if (e != i0 && p[e] > p1) { p1 = p[e]; i1 = e; }
    float inv = 1.f / (p0 + p1 + ps * 1e-9f);
    if (lane == 0) {
      sm.rt.i0[slot] = i0; sm.rt.i1[slot] = i1;
      sm.rt.w0[slot] = p0 * inv; sm.rt.w1[slot] = p1 * inv;
      atomicAdd(&sm.rt.hist[i0], 1); atomicAdd(&sm.rt.hist[i1], 1);
    }
  }
  __syncthreads();
  if (tid < NEXP) sm.rt.base_[tid] = atomicAdd(&cnt[tid], sm.rt.hist[tid]);
  __syncthreads();
  if (tid < 64) {
    int b = rb * 64 + tid;
    int i0 = sm.rt.i0[tid], i1 = sm.rt.i1[tid];
    int s0 = sm.rt.base_[i0] + atomicAdd(&sm.rt.loc[i0], 1);
    tok[i0 * NTOK + s0] = b; wgt[i0 * NTOK + s0] = sm.rt.w0[tid];
    int s1 = sm.rt.base_[i1] + atomicAdd(&sm.rt.loc[i1], 1);
    tok[i1 * NTOK + s1] = b; wgt[i1 * NTOK + s1] = sm.rt.w1[tid];
  }
}

// --------- fused grouped expert kernel: out += w * (relu(x W1 + b1) W2 + b2)
// Round-0 schedule (single-buffered stage-then-drain, 2 barriers/phase —
// proven best) with LDS shrunk 74->40 KB for 4 blocks/CU of TLP cover:
//  - W1 slices (GEMM1) and W2 K=32 pair-row chunks (GEMM2, 4 phases) share
//    one 16 KB pool.
//  - stok/swgt LDS arrays removed: token ids/weights read straight from
//    global (staging ptrs once at start; epilogue pairs hit L2).
// Tile M=64 x N=256, HC=128, BK=64. 4 waves 2x2. LDS exactly 40960 B.
__global__ __launch_bounds__(256, 4) void k_moe(
    const unsigned short* __restrict__ xb, const unsigned short* __restrict__ w1t,
    const unsigned short* __restrict__ w2t, const float* __restrict__ b1,
    const float* __restrict__ b2, const int* __restrict__ cnt,
    const int* __restrict__ tok, const float* __restrict__ wgt,
    float* __restrict__ out) {
  int e = blockIdx.y;
  int n = cnt[e];
  int tile = blockIdx.x;
  if (tile * 64 >= n) return;
  __shared__ unsigned short xa[4096];   //  8 KB  x k-slice [64 tok x 64 k]
  __shared__ unsigned short wp[8192];   // 16 KB  W1 [128h x 64k] / W2 [256o x 32h pair-row]
  __shared__ unsigned short hs[8192];   // 16 KB  h chunk [64 tok x 128 h]
  int tid = threadIdx.x;
  int wave = tid >> 6, lane = tid & 63, quad = lane >> 4, l16 = lane & 15;
  int wm = wave & 1, wn = wave >> 1;
  int srow = tid >> 3;                          // 0..31
  int c8 = (tid & 7) ^ (srow & 7);              // inverse XOR swizzle on source
  // ---- token ids for the two X staging rows this thread serves
  int i0 = tile * 64 + srow, i1 = i0 + 32;
  int t0 = i0 < n ? tok[e * NTOK + i0] : 0;
  int t1 = i1 < n ? tok[e * NTOK + i1] : 0;
  // ---- staging pointers
  const unsigned short* gx0 = xb + (size_t)t0 * DIN + c8 * 8;
  const unsigned short* gx1 = xb + (size_t)t1 * DIN + c8 * 8;
  const unsigned short* w1e = w1t + (size_t)e * HID * DIN;   // [h][d]
  const unsigned short* w2e = w2t + (size_t)e * DOUT * HID;  // [o][h]
  const unsigned short* gb1 = w1e + (size_t)srow * DIN + c8 * 8;
  // W2 pair-row chunk layout: slot sIdx=s*256+tid -> o = 2*(s*32+srow)+(c8>>2),
  // h-group = c8&3 within the 32-h chunk; 4 loads/thread = full 16 KB chunk.
  const unsigned short* gb2 = w2e + (size_t)(2 * srow + (c8 >> 2)) * HID + (c8 & 3) * 8;
  // ---- fragment row indices
  int ra0 = wm * 32 + l16, ra1 = ra0 + 16;              // A rows (tokens)
  int rh0 = wn * 64 + l16;                              // GEMM1 B rows (h)
  int ro0 = wn * 128 + l16;                             // GEMM2 B rows (o)
  f32x4 acc2[2][8];
#pragma unroll
  for (int nt = 0; nt < 8; nt++) {
    float bv = b2[e * DOUT + wn * 128 + nt * 16 + l16];
    acc2[0][nt] = (f32x4){bv, bv, bv, bv};
    acc2[1][nt] = (f32x4){bv, bv, bv, bv};
  }
  for (int hc = 0; hc < 8; hc++) {
    // ============ GEMM1: h[64x128] = x[64x512] @ W1T-chunk, 8 phases ========
    f32x4 acc1[2][4];
#pragma unroll
    for (int nt = 0; nt < 4; nt++) {
      float bv = b1[e * HID + hc * 128 + wn * 64 + nt * 16 + l16];
      acc1[0][nt] = (f32x4){bv, bv, bv, bv};
      acc1[1][nt] = (f32x4){bv, bv, bv, bv};
    }
    for (int ks = 0; ks < 8; ks++) {
      __syncthreads();                         // prev readers of xa/wp done
      gld16(xa + (size_t)tid * 8, gx0 + ks * 64);
      gld16(xa + ((size_t)tid + 256) * 8, gx1 + ks * 64);
#pragma unroll
      for (int s = 0; s < 4; s++)
        gld16(wp + ((size_t)s * 256 + tid) * 8,
              gb1 + (size_t)hc * 128 * DIN + (size_t)s * 32 * DIN + ks * 64);
      __syncthreads();                         // DMA drained (vmcnt0 @ barrier)
#pragma unroll
      for (int ki2 = 0; ki2 < 2; ki2++) {
        int cq = ki2 * 4 + quad;
        short8 af[2], bf[4];
        af[0] = *(const short8*)(xa + (ra0 * 8 + (cq ^ (ra0 & 7))) * 8);
        af[1] = *(const short8*)(xa + (ra1 * 8 + (cq ^ (ra1 & 7))) * 8);
#pragma unroll
        for (int nt = 0; nt < 4; nt++) {
          int r = rh0 + nt * 16;
          bf[nt] = *(const short8*)(wp + (r * 8 + (cq ^ (r & 7))) * 8);
        }
#pragma unroll
        for (int mt = 0; mt < 2; mt++)
#pragma unroll
          for (int nt = 0; nt < 4; nt++)
            acc1[mt][nt] = __builtin_amdgcn_mfma_f32_16x16x32_bf16(
                af[mt], bf[nt], acc1[mt][nt], 0, 0, 0);
      }
    }
    // relu + bf16 -> swizzled h LDS (row = token, 16 chunks of 8)
#pragma unroll
    for (int mt = 0; mt < 2; mt++) {
#pragma unroll
      for (int nt = 0; nt < 4; nt++) {
        int col = wn * 64 + nt * 16 + l16;
        int c16 = col >> 3, co = col & 7;
#pragma unroll
        for (int r4 = 0; r4 < 4; r4++) {
          int r = wm * 32 + mt * 16 + quad * 4 + r4;
          float v = acc1[mt][nt][r4];
          hs[(r * 16 + (c16 ^ (r & 15))) * 8 + co] = f2bf(v > 0.f ? v : 0.f);
        }
      }
    }
    // ============ GEMM2: out[64x256] += h @ W2T-chunk, 4 phases (K=32) ======
    for (int k2 = 0; k2 < 4; k2++) {
      __syncthreads();                         // hs flushed; prev wp readers done
#pragma unroll
      for (int s = 0; s < 4; s++)
        gld16(wp + ((size_t)s * 256 + tid) * 8,
              gb2 + (size_t)s * 64 * HID + hc * 128 + k2 * 32);
      __syncthreads();                         // DMA drained
      int c16 = k2 * 4 + quad;
      short8 af[2], bf[8];
      af[0] = *(const short8*)(hs + (ra0 * 16 + (c16 ^ (ra0 & 15))) * 8);
      af[1] = *(const short8*)(hs + (ra1 * 16 + (c16 ^ (ra1 & 15))) * 8);
#pragma unroll
      for (int nt = 0; nt < 8; nt++) {
        int rr = ro0 + nt * 16;
        int inner = (((rr & 1) << 2) | quad) ^ ((rr >> 1) & 7);
        bf[nt] = *(const short8*)(wp + ((rr >> 1) * 8 + inner) * 8);
      }
#pragma unroll
      for (int mt = 0; mt < 2; mt++)
#pragma unroll
        for (int nt = 0; nt < 8; nt++)
          acc2[mt][nt] = __builtin_amdgcn_mfma_f32_16x16x32_bf16(
              af[mt], bf[nt], acc2[mt][nt], 0, 0, 0);
    }
  }
  // ---- epilogue: gate-weighted atomic accumulate (tok/wgt straight from L2)
#pragma unroll
  for (int mt = 0; mt < 2; mt++) {
#pragma unroll
    for (int r4 = 0; r4 < 4; r4++) {
      int m = wm * 32 + mt * 16 + quad * 4 + r4;
      int idx = tile * 64 + m;
      if (idx < n) {
        float wv = wgt[e * NTOK + idx];
        int t = tok[e * NTOK + idx];
        float* op = out + (size_t)t * DOUT + wn * 128 + l16;
#pragma unroll
        for (int nt = 0; nt < 8; nt++)
          atomicAdd(op + nt * 16, acc2[mt][nt][r4] * wv);
      }
    }
  }
}

extern "C" void kernel_launch(void* const* d_in, const int* in_sizes, int n_in,
                              void* d_out, int out_size, void* d_ws, size_t ws_size,
                              hipStream_t stream) {
  (void)in_sizes; (void)n_in; (void)ws_size; (void)out_size;
  const float* x     = (const float*)d_in[0];
  const float* spike = (const float*)d_in[1];
  const float* Wr    = (const float*)d_in[2];
  const float* br    = (const float*)d_in[3];
  const float* W1    = (const float*)d_in[4];
  const float* b1    = (const float*)d_in[5];
  const float* W2    = (const float*)d_in[6];
  const float* b2    = (const float*)d_in[7];
  float* out = (float*)d_out;
  char* ws = (char*)d_ws;
  unsigned short* xb  = (unsigned short*)(ws + 0);          // 33,554,432
  unsigned short* w1t = (unsigned short*)(ws + 33554432);   // 10,485,760
  unsigned short* w2t = (unsigned short*)(ws + 44040192);   //  5,242,880
  int*   cnt          = (int*)(ws + 49303552);              //         64
  int*   tok          = (int*)(ws + 49303616);              //  1,310,720
  float* wgt          = (float*)(ws + 50614336);            //  1,310,720

  hipMemsetAsync(cnt, 0, 64, stream);
  k_prep<<<TW1_BLOCKS + TW2_BLOCKS + RT_BLOCKS, 256, 0, stream>>>(
      x, spike, Wr, br, W1, W2, xb, w1t, w2t, cnt, tok, wgt, out);
  k_moe<<<dim3(512, NEXP), 256, 0, stream>>>(xb, w1t, w2t, b1, b2, cnt, tok, wgt, out);
}

// Round 7
// 410.456 us; speedup vs baseline: 1.3280x; 1.3280x over previous
//
#include <hip/hip_runtime.h>
#include <hip/hip_bf16.h>
#include <stdint.h>
#include <stddef.h>

typedef __attribute__((ext_vector_type(8))) short short8;
typedef __attribute__((ext_vector_type(4))) float f32x4;

#define NTOK 32768
#define DIN 512
#define HID 1024
#define DOUT 256
#define NEXP 10

#define TW1_BLOCKS 1280   // W1 transpose: 16x8 tiles x 10 experts
#define TW2_BLOCKS 640    // W2 transpose: 4x16 tiles x 10 experts
#define RT_BLOCKS  512    // router: 64 tokens/block

__device__ __forceinline__ unsigned short f2bf(float f) {
  unsigned int u = __float_as_uint(f);
  u += 0x7fffu + ((u >> 16) & 1u);   // round-to-nearest-even
  return (unsigned short)(u >> 16);
}

__device__ __forceinline__ unsigned long long pack4bf(float4 v) {
  return (unsigned long long)f2bf(v.x) | ((unsigned long long)f2bf(v.y) << 16) |
         ((unsigned long long)f2bf(v.z) << 32) | ((unsigned long long)f2bf(v.w) << 48);
}

// async 16B/lane global->LDS DMA (dest = wave-uniform base + lane*16)
__device__ __forceinline__ void gld16(void* lds, const void* g) {
  __builtin_amdgcn_global_load_lds(
      (const __attribute__((address_space(1))) unsigned int*)g,
      (__attribute__((address_space(3))) unsigned int*)lds, 16, 0, 0);
}

union PrepSmem {
  unsigned short tile[64][72];
  struct {
    int i0[64]; int i1[64]; float w0[64]; float w1[64];
    int hist[NEXP]; int base_[NEXP]; int loc[NEXP];
  } rt;
};

// ---- fused prep: W1/W2 transpose+convert, router (+out zeroing), Wr inline ----
__global__ __launch_bounds__(256) void k_prep(
    const float* __restrict__ x, const float* __restrict__ spike,
    const float* __restrict__ Wr, const float* __restrict__ br,
    const float* __restrict__ W1, const float* __restrict__ W2,
    unsigned short* __restrict__ xb, unsigned short* __restrict__ w1t,
    unsigned short* __restrict__ w2t, int* __restrict__ cnt,
    int* __restrict__ tok, float* __restrict__ wgt, float* __restrict__ out) {
  __shared__ PrepSmem sm;
  int bid = blockIdx.x;
  int tid = threadIdx.x;

  if (bid < TW1_BLOCKS + TW2_BLOCKS) {
    // ---------------- transpose path: [E][R][C] f32 -> [E][C][R] bf16 -------
    const float* in; unsigned short* outp; int R, C, bx, by, bz;
    if (bid < TW1_BLOCKS) {
      int r = bid; bz = r >> 7; r &= 127; by = r >> 4; bx = r & 15;
      in = W1; outp = w1t; R = DIN; C = HID;
    } else {
      int r = bid - TW1_BLOCKS; bz = r >> 6; r &= 63; by = r >> 2; bx = r & 3;
      in = W2; outp = w2t; R = HID; C = DOUT;
    }
    const float* ip = in + ((size_t)bz * R + by * 64) * C + bx * 64;
    int rr = tid >> 2, c0 = (tid & 3) * 16;
    const float* p = ip + (size_t)rr * C + c0;
#pragma unroll
    for (int j = 0; j < 16; j += 4) {
      float4 v = *(const float4*)(p + j);
      sm.tile[rr][c0 + j + 0] = f2bf(v.x);
      sm.tile[rr][c0 + j + 1] = f2bf(v.y);
      sm.tile[rr][c0 + j + 2] = f2bf(v.z);
      sm.tile[rr][c0 + j + 3] = f2bf(v.w);
    }
    __syncthreads();
    unsigned short* op = outp + ((size_t)bz * C + bx * 64) * R + by * 64;
    int c = tid >> 2, r0 = (tid & 3) * 16;
    unsigned short* q = op + (size_t)c * R + r0;
    union { short8 v; unsigned short u[8]; } t0, t1;
#pragma unroll
    for (int j = 0; j < 8; j++) { t0.u[j] = sm.tile[r0 + j][c]; t1.u[j] = sm.tile[r0 + 8 + j][c]; }
    *(short8*)(q) = t0.v;
    *(short8*)(q + 8) = t1.v;
    return;
  }

  // ---------------- router path (also zeroes its out slice) -----------------
  int rb = bid - (TW1_BLOCKS + TW2_BLOCKS);
  int wave = tid >> 6, lane = tid & 63;
  {
    float4 z = {0.f, 0.f, 0.f, 0.f};
    float4* ob = (float4*)(out + (size_t)rb * 64 * DOUT);
#pragma unroll
    for (int i = 0; i < 16; i++) ob[i * 256 + tid] = z;   // 64*256 floats
  }
  if (tid < NEXP) { sm.rt.hist[tid] = 0; sm.rt.loc[tid] = 0; }
  __syncthreads();
  // preload router weights transposed from Wr [512][10] into registers
  float4 wv[NEXP][2];
  float brr[NEXP];
#pragma unroll
  for (int e = 0; e < NEXP; e++) {
    brr[e] = br[e];
#pragma unroll
    for (int h = 0; h < 2; h++) {
      int d0 = h * 256 + lane * 4;
      wv[e][h] = (float4){Wr[(size_t)(d0 + 0) * NEXP + e], Wr[(size_t)(d0 + 1) * NEXP + e],
                          Wr[(size_t)(d0 + 2) * NEXP + e], Wr[(size_t)(d0 + 3) * NEXP + e]};
    }
  }
  for (int t = 0; t < 16; t++) {
    int slot = wave * 16 + t;
    int b = rb * 64 + slot;
    const float4* xr4 = (const float4*)(x + (size_t)b * DIN);
    float4 xv0 = xr4[lane], xv1 = xr4[64 + lane];
    *(unsigned long long*)(xb + (size_t)b * DIN + lane * 4) = pack4bf(xv0);
    *(unsigned long long*)(xb + (size_t)b * DIN + 256 + lane * 4) = pack4bf(xv1);
    float lg[NEXP];
#pragma unroll
    for (int e = 0; e < NEXP; e++) {
      lg[e] = xv0.x * wv[e][0].x + xv0.y * wv[e][0].y + xv0.z * wv[e][0].z + xv0.w * wv[e][0].w +
              xv1.x * wv[e][1].x + xv1.y * wv[e][1].y + xv1.z * wv[e][1].z + xv1.w * wv[e][1].w;
    }
#pragma unroll
    for (int off = 32; off > 0; off >>= 1) {
#pragma unroll
      for (int e = 0; e < NEXP; e++) lg[e] += __shfl_xor(lg[e], off);
    }
    float sv = spike[(size_t)b * 16 + (lane & 15)];
    sv += __shfl_xor(sv, 8); sv += __shfl_xor(sv, 4);
    sv += __shfl_xor(sv, 2); sv += __shfl_xor(sv, 1);
    float avg = sv * 0.0625f;
#pragma unroll
    for (int e = 0; e < NEXP; e++) lg[e] += brr[e];
    lg[8] += avg; lg[9] += avg;
    float mx = lg[0];
#pragma unroll
    for (int e = 1; e < NEXP; e++) mx = fmaxf(mx, lg[e]);
    float p[NEXP], ps = 0.f;
#pragma unroll
    for (int e = 0; e < NEXP; e++) { p[e] = __expf(lg[e] - mx); ps += p[e]; }
    int i0 = 0; float p0 = p[0];
#pragma unroll
    for (int e = 1; e < NEXP; e++) if (p[e] > p0) { p0 = p[e]; i0 = e; }
    float p1 = -1.f; int i1 = 0;
#pragma unroll
    for (int e = 0; e < NEXP; e++) if (e != i0 && p[e] > p1) { p1 = p[e]; i1 = e; }
    float inv = 1.f / (p0 + p1 + ps * 1e-9f);
    if (lane == 0) {
      sm.rt.i0[slot] = i0; sm.rt.i1[slot] = i1;
      sm.rt.w0[slot] = p0 * inv; sm.rt.w1[slot] = p1 * inv;
      atomicAdd(&sm.rt.hist[i0], 1); atomicAdd(&sm.rt.hist[i1], 1);
    }
  }
  __syncthreads();
  if (tid < NEXP) sm.rt.base_[tid] = atomicAdd(&cnt[tid], sm.rt.hist[tid]);
  __syncthreads();
  if (tid < 64) {
    int b = rb * 64 + tid;
    int i0 = sm.rt.i0[tid], i1 = sm.rt.i1[tid];
    int s0 = sm.rt.base_[i0] + atomicAdd(&sm.rt.loc[i0], 1);
    tok[i0 * NTOK + s0] = b; wgt[i0 * NTOK + s0] = sm.rt.w0[tid];
    int s1 = sm.rt.base_[i1] + atomicAdd(&sm.rt.loc[i1], 1);
    tok[i1 * NTOK + s1] = b; wgt[i1 * NTOK + s1] = sm.rt.w1[tid];
  }
}

// --------- fused grouped expert kernel: out += w * (relu(x W1 + b1) W2 + b2)
// Round-0 schedule (single-buffered stage-then-drain, 2 barriers/phase) with
// LDS shrunk 74->40 KB. __launch_bounds__(256,2): compiler lands ~96-124 VGPR
// (as rounds 0/5) => 4 waves/SIMD quantum => occupancy limiter is LDS =
// 4 blocks/CU (2x round-0 TLP cover for every drain). NOTE: (256,4) forced
// VGPR=64 and spilled accumulators to scratch (+550 MB HBM) — never cap
// below the ~124 VGPR this body needs.
// Tile M=64 x N=256, HC=128, BK=64. 4 waves 2x2. LDS exactly 40960 B.
__global__ __launch_bounds__(256, 2) void k_moe(
    const unsigned short* __restrict__ xb, const unsigned short* __restrict__ w1t,
    const unsigned short* __restrict__ w2t, const float* __restrict__ b1,
    const float* __restrict__ b2, const int* __restrict__ cnt,
    const int* __restrict__ tok, const float* __restrict__ wgt,
    float* __restrict__ out) {
  int e = blockIdx.y;
  int n = cnt[e];
  int tile = blockIdx.x;
  if (tile * 64 >= n) return;
  __shared__ unsigned short xa[4096];   //  8 KB  x k-slice [64 tok x 64 k]
  __shared__ unsigned short wp[8192];   // 16 KB  W1 [128h x 64k] / W2 [256o x 32h pair-row]
  __shared__ unsigned short hs[8192];   // 16 KB  h chunk [64 tok x 128 h]
  int tid = threadIdx.x;
  int wave = tid >> 6, lane = tid & 63, quad = lane >> 4, l16 = lane & 15;
  int wm = wave & 1, wn = wave >> 1;
  int srow = tid >> 3;                          // 0..31
  int c8 = (tid & 7) ^ (srow & 7);              // inverse XOR swizzle on source
  // ---- token ids for the two X staging rows this thread serves
  int i0 = tile * 64 + srow, i1 = i0 + 32;
  int t0 = i0 < n ? tok[e * NTOK + i0] : 0;
  int t1 = i1 < n ? tok[e * NTOK + i1] : 0;
  // ---- staging pointers
  const unsigned short* gx0 = xb + (size_t)t0 * DIN + c8 * 8;
  const unsigned short* gx1 = xb + (size_t)t1 * DIN + c8 * 8;
  const unsigned short* w1e = w1t + (size_t)e * HID * DIN;   // [h][d]
  const unsigned short* w2e = w2t + (size_t)e * DOUT * HID;  // [o][h]
  const unsigned short* gb1 = w1e + (size_t)srow * DIN + c8 * 8;
  // W2 pair-row chunk layout: slot sIdx=s*256+tid -> o = 2*(s*32+srow)+(c8>>2),
  // h-group = c8&3 within the 32-h chunk; 4 loads/thread = full 16 KB chunk.
  const unsigned short* gb2 = w2e + (size_t)(2 * srow + (c8 >> 2)) * HID + (c8 & 3) * 8;
  // ---- fragment row indices
  int ra0 = wm * 32 + l16, ra1 = ra0 + 16;              // A rows (tokens)
  int rh0 = wn * 64 + l16;                              // GEMM1 B rows (h)
  int ro0 = wn * 128 + l16;                             // GEMM2 B rows (o)
  f32x4 acc2[2][8];
#pragma unroll
  for (int nt = 0; nt < 8; nt++) {
    float bv = b2[e * DOUT + wn * 128 + nt * 16 + l16];
    acc2[0][nt] = (f32x4){bv, bv, bv, bv};
    acc2[1][nt] = (f32x4){bv, bv, bv, bv};
  }
  for (int hc = 0; hc < 8; hc++) {
    // ============ GEMM1: h[64x128] = x[64x512] @ W1T-chunk, 8 phases ========
    f32x4 acc1[2][4];
#pragma unroll
    for (int nt = 0; nt < 4; nt++) {
      float bv = b1[e * HID + hc * 128 + wn * 64 + nt * 16 + l16];
      acc1[0][nt] = (f32x4){bv, bv, bv, bv};
      acc1[1][nt] = (f32x4){bv, bv, bv, bv};
    }
    for (int ks = 0; ks < 8; ks++) {
      __syncthreads();                         // prev readers of xa/wp done
      gld16(xa + (size_t)tid * 8, gx0 + ks * 64);
      gld16(xa + ((size_t)tid + 256) * 8, gx1 + ks * 64);
#pragma unroll
      for (int s = 0; s < 4; s++)
        gld16(wp + ((size_t)s * 256 + tid) * 8,
              gb1 + (size_t)hc * 128 * DIN + (size_t)s * 32 * DIN + ks * 64);
      __syncthreads();                         // DMA drained (vmcnt0 @ barrier)
#pragma unroll
      for (int ki2 = 0; ki2 < 2; ki2++) {
        int cq = ki2 * 4 + quad;
        short8 af[2], bf[4];
        af[0] = *(const short8*)(xa + (ra0 * 8 + (cq ^ (ra0 & 7))) * 8);
        af[1] = *(const short8*)(xa + (ra1 * 8 + (cq ^ (ra1 & 7))) * 8);
#pragma unroll
        for (int nt = 0; nt < 4; nt++) {
          int r = rh0 + nt * 16;
          bf[nt] = *(const short8*)(wp + (r * 8 + (cq ^ (r & 7))) * 8);
        }
#pragma unroll
        for (int mt = 0; mt < 2; mt++)
#pragma unroll
          for (int nt = 0; nt < 4; nt++)
            acc1[mt][nt] = __builtin_amdgcn_mfma_f32_16x16x32_bf16(
                af[mt], bf[nt], acc1[mt][nt], 0, 0, 0);
      }
    }
    // relu + bf16 -> swizzled h LDS (row = token, 16 chunks of 8)
#pragma unroll
    for (int mt = 0; mt < 2; mt++) {
#pragma unroll
      for (int nt = 0; nt < 4; nt++) {
        int col = wn * 64 + nt * 16 + l16;
        int c16 = col >> 3, co = col & 7;
#pragma unroll
        for (int r4 = 0; r4 < 4; r4++) {
          int r = wm * 32 + mt * 16 + quad * 4 + r4;
          float v = acc1[mt][nt][r4];
          hs[(r * 16 + (c16 ^ (r & 15))) * 8 + co] = f2bf(v > 0.f ? v : 0.f);
        }
      }
    }
    // ============ GEMM2: out[64x256] += h @ W2T-chunk, 4 phases (K=32) ======
    for (int k2 = 0; k2 < 4; k2++) {
      __syncthreads();                         // hs flushed; prev wp readers done
#pragma unroll
      for (int s = 0; s < 4; s++)
        gld16(wp + ((size_t)s * 256 + tid) * 8,
              gb2 + (size_t)s * 64 * HID + hc * 128 + k2 * 32);
      __syncthreads();                         // DMA drained
      int c16 = k2 * 4 + quad;
      short8 af[2], bf[8];
      af[0] = *(const short8*)(hs + (ra0 * 16 + (c16 ^ (ra0 & 15))) * 8);
      af[1] = *(const short8*)(hs + (ra1 * 16 + (c16 ^ (ra1 & 15))) * 8);
#pragma unroll
      for (int nt = 0; nt < 8; nt++) {
        int rr = ro0 + nt * 16;
        int inner = (((rr & 1) << 2) | quad) ^ ((rr >> 1) & 7);
        bf[nt] = *(const short8*)(wp + ((rr >> 1) * 8 + inner) * 8);
      }
#pragma unroll
      for (int mt = 0; mt < 2; mt++)
#pragma unroll
        for (int nt = 0; nt < 8; nt++)
          acc2[mt][nt] = __builtin_amdgcn_mfma_f32_16x16x32_bf16(
              af[mt], bf[nt], acc2[mt][nt], 0, 0, 0);
    }
  }
  // ---- epilogue: gate-weighted atomic accumulate (tok/wgt straight from L2)
#pragma unroll
  for (int mt = 0; mt < 2; mt++) {
#pragma unroll
    for (int r4 = 0; r4 < 4; r4++) {
      int m = wm * 32 + mt * 16 + quad * 4 + r4;
      int idx = tile * 64 + m;
      if (idx < n) {
        float wv = wgt[e * NTOK + idx];
        int t = tok[e * NTOK + idx];
        float* op = out + (size_t)t * DOUT + wn * 128 + l16;
#pragma unroll
        for (int nt = 0; nt < 8; nt++)
          atomicAdd(op + nt * 16, acc2[mt][nt][r4] * wv);
      }
    }
  }
}

extern "C" void kernel_launch(void* const* d_in, const int* in_sizes, int n_in,
                              void* d_out, int out_size, void* d_ws, size_t ws_size,
                              hipStream_t stream) {
  (void)in_sizes; (void)n_in; (void)ws_size; (void)out_size;
  const float* x     = (const float*)d_in[0];
  const float* spike = (const float*)d_in[1];
  const float* Wr    = (const float*)d_in[2];
  const float* br    = (const float*)d_in[3];
  const float* W1    = (const float*)d_in[4];
  const float* b1    = (const float*)d_in[5];
  const float* W2    = (const float*)d_in[6];
  const float* b2    = (const float*)d_in[7];
  float* out = (float*)d_out;
  char* ws = (char*)d_ws;
  unsigned short* xb  = (unsigned short*)(ws + 0);          // 33,554,432
  unsigned short* w1t = (unsigned short*)(ws + 33554432);   // 10,485,760
  unsigned short* w2t = (unsigned short*)(ws + 44040192);   //  5,242,880
  int*   cnt          = (int*)(ws + 49303552);              //         64
  int*   tok          = (int*)(ws + 49303616);              //  1,310,720
  float* wgt          = (float*)(ws + 50614336);            //  1,310,720

  hipMemsetAsync(cnt, 0, 64, stream);
  k_prep<<<TW1_BLOCKS + TW2_BLOCKS + RT_BLOCKS, 256, 0, stream>>>(
      x, spike, Wr, br, W1, W2, xb, w1t, w2t, cnt, tok, wgt, out);
  k_moe<<<dim3(512, NEXP), 256, 0, stream>>>(xb, w1t, w2t, b1, b2, cnt, tok, wgt, out);
}